// Round 6
// baseline (327.579 us; speedup 1.0000x reference)
//
#include <hip/hip_runtime.h>
#include <hip/hip_bf16.h>

#define IN_CH 256
#define OUT_CH 128
#define CHUNK 1024
#define PREP_BLOCKS 16

using bf16x8 = __attribute__((ext_vector_type(8))) __bf16;
using f32x16 = __attribute__((ext_vector_type(16))) float;
using f32x4  = __attribute__((ext_vector_type(4))) float;

__device__ __forceinline__ unsigned int f2bf(float f) {
    union { float f; unsigned u; } v; v.f = f;
    unsigned r = v.u + 0x7fffu + ((v.u >> 16) & 1u);
    return r >> 16;
}
__device__ __forceinline__ float bf2f(unsigned short u) {
    union { unsigned u; float f; } v; v.u = ((unsigned)u) << 16;
    return v.f;
}

// ---------------- A) fused: prep_w (blocks 0..15) + dst histogram ----------------
__global__ void __launch_bounds__(256) prep_hist_kernel(
    const float* __restrict__ W, unsigned short* __restrict__ Wfrag,
    const int* __restrict__ edge_dst, int* __restrict__ counts, int n_edges) {
    if (blockIdx.x < PREP_BLOCKS) {
        const int flat = blockIdx.x * 256 + threadIdx.x;  // 0..4095
        const int l = flat & 63;
        const int ks = (flat >> 6) & 15;
        const int c = flat >> 10;
        const int row = c * 32 + (l & 31);
        const int col0 = ks * 16 + 8 * (l >> 5);
        const float* src = W + (size_t)row * IN_CH + col0;
        uint4 o;
        o.x = f2bf(src[0]) | (f2bf(src[1]) << 16);
        o.y = f2bf(src[2]) | (f2bf(src[3]) << 16);
        o.z = f2bf(src[4]) | (f2bf(src[5]) << 16);
        o.w = f2bf(src[6]) | (f2bf(src[7]) << 16);
        *reinterpret_cast<uint4*>(Wfrag + (size_t)flat * 8) = o;
    } else {
        int e = (blockIdx.x - PREP_BLOCKS) * 256 + threadIdx.x;
        if (e < n_edges) atomicAdd(&counts[edge_dst[e]], 1);
    }
}

// ---------------- B) hierarchical exclusive scan ----------------
__global__ void __launch_bounds__(256) scan_chunk_sums(
    const int* __restrict__ counts, int* __restrict__ partials, int n) {
    __shared__ int sdata[256];
    const int base = blockIdx.x * CHUNK;
    int sum = 0;
    for (int i = threadIdx.x; i < CHUNK; i += 256) {
        int idx = base + i;
        sum += (idx < n) ? counts[idx] : 0;
    }
    sdata[threadIdx.x] = sum;
    __syncthreads();
    for (int s = 128; s > 0; s >>= 1) {
        if (threadIdx.x < s) sdata[threadIdx.x] += sdata[threadIdx.x + s];
        __syncthreads();
    }
    if (threadIdx.x == 0) partials[blockIdx.x] = sdata[0];
}

__global__ void __launch_bounds__(128) scan_partials_kernel(int* partials, int nchunk) {
    __shared__ int sp[256];
    int tid = threadIdx.x;
    for (int i = tid; i < nchunk; i += 128) sp[i] = partials[i];
    __syncthreads();
    if (tid == 0) {
        int run = 0;
        for (int c = 0; c < nchunk; ++c) { int t = sp[c]; sp[c] = run; run += t; }
    }
    __syncthreads();
    for (int i = tid; i < nchunk; i += 128) partials[i] = sp[i];
}

__global__ void __launch_bounds__(256) scan_within_kernel(
    int* __restrict__ cursor, int* __restrict__ offsets,
    const int* __restrict__ partials, int n) {
    __shared__ int tsum[256];
    const int tid = threadIdx.x;
    const int i0 = blockIdx.x * CHUNK + tid * 4;
    int vals[4];
    int loc = 0;
#pragma unroll
    for (int j = 0; j < 4; ++j) {
        int idx = i0 + j;
        vals[j] = (idx < n) ? cursor[idx] : 0;
        loc += vals[j];
    }
    tsum[tid] = loc;
    __syncthreads();
    int inc = loc;
    for (int s = 1; s < 256; s <<= 1) {
        int y = (tid >= s) ? tsum[tid - s] : 0;
        __syncthreads();
        inc += y;
        tsum[tid] = inc;
        __syncthreads();
    }
    int run = partials[blockIdx.x] + (inc - loc);
#pragma unroll
    for (int j = 0; j < 4; ++j) {
        int idx = i0 + j;
        if (idx < n) { offsets[idx] = run; cursor[idx] = run; }
        run += vals[j];
    }
}

// ---------------- C) fused: edge scatter (blocks 0..eblocks) + linear MFMA ----------------
__global__ void __launch_bounds__(256) scatter_linear_kernel(
    const int* __restrict__ edge_src, const int* __restrict__ edge_dst,
    const float* __restrict__ edge_weight, int* __restrict__ cursor,
    unsigned long long* __restrict__ records, int n_edges, int eblocks,
    const float* __restrict__ x, const unsigned short* __restrict__ Wfrag,
    const float* __restrict__ b, unsigned short* __restrict__ h, int n_nodes) {
    if ((int)blockIdx.x < eblocks) {
        // ---- scatter: one 8B nontemporal record per edge ----
        int e = blockIdx.x * 256 + threadIdx.x;
        if (e < n_edges) {
            int d = edge_dst[e];
            int pos = atomicAdd(&cursor[d], 1);
            unsigned long long rec =
                ((unsigned long long)__float_as_uint(edge_weight[e]) << 32) |
                (unsigned int)edge_src[e];
            __builtin_nontemporal_store(rec, &records[pos]);
        }
        return;
    }
    // ---- linear: h = bf16(x @ W.T + b) via 32x32x16 bf16 MFMA ----
    const int lb = blockIdx.x - eblocks;
    const int tid = threadIdx.x;
    const int w = tid >> 6, l = tid & 63;
    const int l31 = l & 31, lh = l >> 5;
    const int node0 = lb * 128 + w * 32;

    int arow = node0 + l31;
    if (arow > n_nodes - 1) arow = n_nodes - 1;
    const float* xrow = x + (size_t)arow * IN_CH + 8 * lh;
    const uint4* wf = reinterpret_cast<const uint4*>(Wfrag);

    f32x16 acc0 = {}, acc1 = {}, acc2 = {}, acc3 = {};

#pragma unroll 4
    for (int ks = 0; ks < 16; ++ks) {
        float4 a0 = *reinterpret_cast<const float4*>(xrow + ks * 16);
        float4 a1 = *reinterpret_cast<const float4*>(xrow + ks * 16 + 4);
        bf16x8 af;
        af[0] = (__bf16)a0.x; af[1] = (__bf16)a0.y;
        af[2] = (__bf16)a0.z; af[3] = (__bf16)a0.w;
        af[4] = (__bf16)a1.x; af[5] = (__bf16)a1.y;
        af[6] = (__bf16)a1.z; af[7] = (__bf16)a1.w;

        uint4 bw0 = wf[(0 * 16 + ks) * 64 + l];
        uint4 bw1 = wf[(1 * 16 + ks) * 64 + l];
        uint4 bw2 = wf[(2 * 16 + ks) * 64 + l];
        uint4 bw3 = wf[(3 * 16 + ks) * 64 + l];

        acc0 = __builtin_amdgcn_mfma_f32_32x32x16_bf16(af, __builtin_bit_cast(bf16x8, bw0), acc0, 0, 0, 0);
        acc1 = __builtin_amdgcn_mfma_f32_32x32x16_bf16(af, __builtin_bit_cast(bf16x8, bw1), acc1, 0, 0, 0);
        acc2 = __builtin_amdgcn_mfma_f32_32x32x16_bf16(af, __builtin_bit_cast(bf16x8, bw2), acc2, 0, 0, 0);
        acc3 = __builtin_amdgcn_mfma_f32_32x32x16_bf16(af, __builtin_bit_cast(bf16x8, bw3), acc3, 0, 0, 0);
    }

    const float bias0 = b[0 + l31], bias1 = b[32 + l31], bias2 = b[64 + l31], bias3 = b[96 + l31];
#pragma unroll
    for (int reg = 0; reg < 16; ++reg) {
        const int r = (reg & 3) + 8 * (reg >> 2) + 4 * lh;
        const int node = node0 + r;
        if (node < n_nodes) {
            unsigned short* hp = h + (size_t)node * OUT_CH;
            __bf16 t0 = (__bf16)(acc0[reg] + bias0);
            __bf16 t1 = (__bf16)(acc1[reg] + bias1);
            __bf16 t2 = (__bf16)(acc2[reg] + bias2);
            __bf16 t3 = (__bf16)(acc3[reg] + bias3);
            hp[0 + l31]  = __builtin_bit_cast(unsigned short, t0);
            hp[32 + l31] = __builtin_bit_cast(unsigned short, t1);
            hp[64 + l31] = __builtin_bit_cast(unsigned short, t2);
            hp[96 + l31] = __builtin_bit_cast(unsigned short, t3);
        }
    }
}

// ---------------- D) segmented reduction: one wave per dst, 4 edge streams ----------------
__global__ void __launch_bounds__(256) agg_kernel(
    const unsigned short* __restrict__ h, const int* __restrict__ offsets,
    const unsigned long long* __restrict__ records,
    float* __restrict__ out, int n_nodes, int n_edges) {
    const int wave = (blockIdx.x * 256 + threadIdx.x) >> 6;
    const int lane = threadIdx.x & 63;
    if (wave >= n_nodes) return;
    const int start = offsets[wave];
    const int end = (wave == n_nodes - 1) ? n_edges : offsets[wave + 1];
    const int sub = lane >> 4;          // 4 parallel edge streams per wave
    const int c8 = (lane & 15) * 8;     // 8 channels per lane

    float a0 = 0.f, a1 = 0.f, a2 = 0.f, a3 = 0.f;
    float a4 = 0.f, a5 = 0.f, a6 = 0.f, a7 = 0.f;
    for (int i = start + sub; i < end; i += 4) {
        const unsigned long long rec = records[i];
        const int s = (int)(rec & 0xffffffffu);
        const float w = __uint_as_float((unsigned int)(rec >> 32));
        const ushort4 hv0 = *reinterpret_cast<const ushort4*>(h + (size_t)s * OUT_CH + c8);
        const ushort4 hv1 = *reinterpret_cast<const ushort4*>(h + (size_t)s * OUT_CH + c8 + 4);
        a0 += w * bf2f(hv0.x); a1 += w * bf2f(hv0.y);
        a2 += w * bf2f(hv0.z); a3 += w * bf2f(hv0.w);
        a4 += w * bf2f(hv1.x); a5 += w * bf2f(hv1.y);
        a6 += w * bf2f(hv1.z); a7 += w * bf2f(hv1.w);
    }
#pragma unroll
    for (int m = 16; m <= 32; m <<= 1) {
        a0 += __shfl_xor(a0, m); a1 += __shfl_xor(a1, m);
        a2 += __shfl_xor(a2, m); a3 += __shfl_xor(a3, m);
        a4 += __shfl_xor(a4, m); a5 += __shfl_xor(a5, m);
        a6 += __shfl_xor(a6, m); a7 += __shfl_xor(a7, m);
    }
    if (lane < 16) {
        float* op = out + (size_t)wave * OUT_CH + c8;
        f32x4 o0 = {a0, a1, a2, a3};
        f32x4 o1 = {a4, a5, a6, a7};
        __builtin_nontemporal_store(o0, reinterpret_cast<f32x4*>(op));
        __builtin_nontemporal_store(o1, reinterpret_cast<f32x4*>(op + 4));
    }
}

extern "C" void kernel_launch(void* const* d_in, const int* in_sizes, int n_in,
                              void* d_out, int out_size, void* d_ws, size_t ws_size,
                              hipStream_t stream) {
    const float* x           = (const float*)d_in[0];
    const int*   edge_src    = (const int*)d_in[1];
    const int*   edge_dst    = (const int*)d_in[2];
    const float* edge_weight = (const float*)d_in[3];
    const float* W           = (const float*)d_in[4];
    const float* b           = (const float*)d_in[5];
    float* out = (float*)d_out;

    const int n_nodes = in_sizes[0] / IN_CH;
    const int n_edges = in_sizes[1];
    const int nchunk = (n_nodes + CHUNK - 1) / CHUNK;

    // workspace layout (8B-aligned blocks first)
    unsigned long long* records = (unsigned long long*)d_ws;            // n_edges * 8B
    unsigned short* h           = (unsigned short*)(records + n_edges); // n_nodes*128 bf16
    int*            offsets     = (int*)(h + (size_t)n_nodes * OUT_CH);
    int*            cursor      = offsets + n_nodes;
    int*            partials    = cursor + n_nodes;
    unsigned short* Wfrag       = (unsigned short*)(partials + 256);    // 64 KB

    hipMemsetAsync(cursor, 0, (size_t)n_nodes * sizeof(int), stream);

    const int eblocks = (n_edges + 255) / 256;
    const int lblocks = (n_nodes + 127) / 128;

    // A) prep_w + histogram (both only read inputs)
    prep_hist_kernel<<<PREP_BLOCKS + eblocks, 256, 0, stream>>>(
        W, Wfrag, edge_dst, cursor, n_edges);

    // B) exclusive scan -> offsets + cursor(write ptrs)
    scan_chunk_sums<<<nchunk, 256, 0, stream>>>(cursor, partials, n_nodes);
    scan_partials_kernel<<<1, 128, 0, stream>>>(partials, nchunk);
    scan_within_kernel<<<nchunk, 256, 0, stream>>>(cursor, offsets, partials, n_nodes);

    // C) scatter + linear fused (independent work, overlapped in one dispatch)
    scatter_linear_kernel<<<eblocks + lblocks, 256, 0, stream>>>(
        edge_src, edge_dst, edge_weight, cursor, records, n_edges, eblocks,
        x, Wfrag, b, h, n_nodes);

    // D) segmented reduction
    const int ablocks = (n_nodes * 64 + 255) / 256;
    agg_kernel<<<ablocks, 256, 0, stream>>>(
        h, offsets, records, out, n_nodes, n_edges);
}